// Round 14
// baseline (53.095 us; speedup 1.0000x reference)
//
#include <hip/hip_runtime.h>
#include <hip/hip_bf16.h>
#include <stdint.h>

typedef __attribute__((ext_vector_type(8)))  __bf16   bf16x8;
typedef __attribute__((ext_vector_type(4)))  float    f32x4;
typedef __attribute__((ext_vector_type(8)))  float    f32x8;

#define NN   2000
#define NK   32
#define NOUT 128

#define GLOBAL_AS __attribute__((address_space(1)))
#define LDS_AS    __attribute__((address_space(3)))
#define SB() __builtin_amdgcn_sched_barrier(0)
#define MFMA16 __builtin_amdgcn_mfma_f32_16x16x32_bf16

// ---------------------------------------------------------------------------
// Prep (verified R12/R13). Blocks [0,NN): x -> xb2h[h][n] 2KB half-tiles in
// 16x16x32 A-frag order + dist -> db bf16. Blocks [NN,NN+65): W -> Wf2
// B-frag order: byte = kstep*8192 + og*1024 + lane*16 + j*2 holds
// W[o=og*16+(l&15)][col(kg=kstep*32+(l>>4)*8+j)].
// ---------------------------------------------------------------------------
__global__ void kprep(const float* __restrict__ x, const float* __restrict__ dist,
                      const float* __restrict__ W,
                      __bf16* __restrict__ xb2h, __bf16* __restrict__ db,
                      __bf16* __restrict__ Wf2) {
  const int t = threadIdx.x;
  if (blockIdx.x < NN) {
    const int n = blockIdx.x;
    const int b  = t >> 3;          // batch 0..31
    const int f0 = (t & 7) << 3;    // feature start 0..56
    const float* src = x + ((size_t)b * NN + n) * 64 + f0;
    f32x8 v = *(const f32x8*)src;
    bf16x8 r;
#pragma unroll
    for (int j = 0; j < 8; ++j) r[j] = (__bf16)v[j];
    const int h = b >> 4, row = b & 15;
    const int off = ((f0 >> 5) << 10) + (((((f0 >> 3) & 3) << 4) + row) << 4);
    *(bf16x8*)((char*)xb2h + ((size_t)(h * NN + n) << 11) + off) = r;
    if (t < NK) db[n * NK + t] = (__bf16)dist[n * NK + t];
  } else {
    const int kstep = blockIdx.x - NN;      // 0..64
#pragma unroll
    for (int pass = 0; pass < 2; ++pass) {
      const int it = t + pass * 256;
      const int og = it >> 6, lane = it & 63;
      const int o  = og * 16 + (lane & 15);
      const int kb = kstep * 32 + ((lane >> 4) << 3);
      bf16x8 r;
#pragma unroll
      for (int j = 0; j < 8; ++j) {
        const int kg = kb + j;
        const int col = (kg < 2048) ? ((kg >> 6) * 65 + (kg & 63)) : ((kg - 2048) * 65 + 64);
        r[j] = (__bf16)W[(size_t)o * 2080 + col];
      }
      *(bf16x8*)((char*)Wf2 + (size_t)kstep * 8192 + og * 1024 + lane * 16) = r;
    }
  }
}

// ---------------------------------------------------------------------------
// Main (traffic A/B vs R13: B-stream halved). Block = (half h, 16 n),
// 512 threads = 8 waves; wave = 2 n x ALL 128 out. Grid 250 (~1 block/CU).
// B-traffic = 250 x 532KB = 133 MB (was 266); A unchanged (irreducible).
// Pipeline (R13-verbatim structure): A depth-3 in 4 named reg banks; B
// depth-2 in 3 LDS bufs; per-wave period ops [A:4, B:2] ->
// steady queue [A(c)4,B(c)2,A(c+1)4,B(c+1)2,A(c+2)4]=16 -> vmcnt(10)
// drains exactly A(c),B(c), 10 stay in flight across the barrier.
// ---------------------------------------------------------------------------
__global__ __launch_bounds__(512, 2) void kmain(
    const int* __restrict__ nbrs, const float* __restrict__ bias,
    const __bf16* __restrict__ xb2h, const __bf16* __restrict__ Wf2,
    const __bf16* __restrict__ db, float* __restrict__ out) {
  __shared__ __align__(16) char lds[3][16384];   // [buf][2 kstep][8 og][1KB]

  const int t    = threadIdx.x;
  const int lane = t & 63;
  const int w    = t >> 6;                    // 0..7
  const int h    = blockIdx.x & 1;
  const int n0   = (blockIdx.x >> 1) * 16 + w * 2;
  const int colo = lane & 15;
  const int rgrp = lane >> 4;

  f32x4 acc[2][8] = {};                       // [np][og], literal-indexed only

  const int myidx = nbrs[(n0 + (lane >> 5)) * NK + (lane & 31)];

  const char* xb = (const char*)xb2h + ((size_t)(h * NN) << 11);
  const char* wf = (const char*)Wf2;

  auto loadA = [&](bf16x8 (*A)[2], int c) {   // 4 loads: 2 np x 2 ks (4KB)
#pragma unroll
    for (int np = 0; np < 2; ++np) {
      const int nb = __builtin_amdgcn_readlane(myidx, np * 32 + c);
      const char* g = xb + ((size_t)nb << 11) + lane * 16;
      A[np][0] = *(const bf16x8*)(g);
      A[np][1] = *(const bf16x8*)(g + 1024);
    }
  };

  auto stageB = [&](int buf, int c) {         // wave w copies its 2KB of 16KB chunk
    const char* g = wf + ((size_t)c << 14) + (w << 11) + lane * 16;
    char* l = &lds[buf][w << 11];
#pragma unroll
    for (int q = 0; q < 2; ++q)
      __builtin_amdgcn_global_load_lds(
          (const GLOBAL_AS uint32_t*)(g + (q << 10)),
          (LDS_AS uint32_t*)(l + (q << 10)), 16, 0, 0);
  };

  auto compute = [&](int buf, bf16x8 (*A)[2]) {
    const char* lb = &lds[buf][lane * 16];
    __builtin_amdgcn_s_setprio(1);
#pragma unroll
    for (int ks = 0; ks < 2; ++ks) {
#pragma unroll
      for (int og = 0; og < 8; ++og) {
        bf16x8 bf = *(const bf16x8*)(lb + (ks << 13) + (og << 10));
        acc[0][og] = MFMA16(A[0][ks], bf, acc[0][og], 0, 0, 0);
        acc[1][og] = MFMA16(A[1][ks], bf, acc[1][og], 0, 0, 0);
      }
    }
    __builtin_amdgcn_s_setprio(0);
  };

  bf16x8 A0[2][2], A1[2][2], A2[2][2], A3[2][2];   // 4 named banks (64 VGPR)

  // prologue: queue = [A(0)4, B(0)2, A(1)4, B(1)2, A(2)4] = 16 ops
  loadA(A0, 0); SB();
  stageB(0, 0); SB();
  loadA(A1, 1); SB();
  stageB(1, 1); SB();
  loadA(A2, 2); SB();

#define BODY(C, ACUR, ALD, BUFC, BUFS)                      \
  asm volatile("s_waitcnt vmcnt(10)" ::: "memory");         \
  __builtin_amdgcn_s_barrier(); SB();                       \
  stageB(BUFS, (C) + 2); SB();                              \
  loadA(ALD, (C) + 3); SB();                                \
  compute(BUFC, ACUR); SB();

  // steady periods 0..28 (bank = C&3, buf = C%3, stage buf = (C+2)%3)
  BODY( 0, A0, A3, 0, 2)  BODY( 1, A1, A0, 1, 0)  BODY( 2, A2, A1, 2, 1)
  BODY( 3, A3, A2, 0, 2)  BODY( 4, A0, A3, 1, 0)  BODY( 5, A1, A0, 2, 1)
  BODY( 6, A2, A1, 0, 2)  BODY( 7, A3, A2, 1, 0)  BODY( 8, A0, A3, 2, 1)
  BODY( 9, A1, A0, 0, 2)  BODY(10, A2, A1, 1, 0)  BODY(11, A3, A2, 2, 1)
  BODY(12, A0, A3, 0, 2)  BODY(13, A1, A0, 1, 0)  BODY(14, A2, A1, 2, 1)
  BODY(15, A3, A2, 0, 2)  BODY(16, A0, A3, 1, 0)  BODY(17, A1, A0, 2, 1)
  BODY(18, A2, A1, 0, 2)  BODY(19, A3, A2, 1, 0)  BODY(20, A0, A3, 2, 1)
  BODY(21, A1, A0, 0, 2)  BODY(22, A2, A1, 1, 0)  BODY(23, A3, A2, 2, 1)
  BODY(24, A0, A3, 0, 2)  BODY(25, A1, A0, 1, 0)  BODY(26, A2, A1, 2, 1)
  BODY(27, A3, A2, 0, 2)  BODY(28, A0, A3, 1, 0)
#undef BODY

  // period 29: entry queue [A29:4,B29:2,A30:4,B30:2,A31:4]=16 -> vmcnt(10)
  asm volatile("s_waitcnt vmcnt(10)" ::: "memory");
  __builtin_amdgcn_s_barrier(); SB();
  stageB(1, 31); SB();
  compute(2, A1); SB();
  // period 30: queue [A30:4,B30:2,A31:4,B31:2]=12 -> drain 6 -> vmcnt(6)
  asm volatile("s_waitcnt vmcnt(6)" ::: "memory");
  __builtin_amdgcn_s_barrier(); SB();
  compute(0, A2); SB();
  // period 31
  asm volatile("s_waitcnt vmcnt(0)" ::: "memory");
  __builtin_amdgcn_s_barrier(); SB();
  compute(1, A3);

  // ---- distance kstep 64: A rows all equal d[n][k-slice]; B direct global
  {
    const char* wt = wf + ((size_t)64 << 13) + lane * 16;
    bf16x8 d0 = *(const bf16x8*)((const char*)db + (size_t)(n0 + 0) * 64 + (rgrp << 4));
    bf16x8 d1 = *(const bf16x8*)((const char*)db + (size_t)(n0 + 1) * 64 + (rgrp << 4));
#pragma unroll
    for (int og = 0; og < 8; ++og) {
      bf16x8 bf = *(const bf16x8*)(wt + (og << 10));
      acc[0][og] = MFMA16(d0, bf, acc[0][og], 0, 0, 0);
      acc[1][og] = MFMA16(d1, bf, acc[1][og], 0, 0, 0);
    }
  }

  // ---- epilogue: D col=lane&15 -> o=og*16+colo, row=(lane>>4)*4+r -> batch
#pragma unroll
  for (int og = 0; og < 8; ++og) {
    const int o = (og << 4) + colo;
    const float bv = bias[o];
#pragma unroll
    for (int r = 0; r < 4; ++r) {
      const int b = (h << 4) + (rgrp << 2) + r;
      float* op = out + ((size_t)b * NN + n0) * NOUT + o;
      op[0]    = acc[0][og][r] + bv;
      op[NOUT] = acc[1][og][r] + bv;
    }
  }
}

// ---------------------------------------------------------------------------
extern "C" void kernel_launch(void* const* d_in, const int* in_sizes, int n_in,
                              void* d_out, int out_size, void* d_ws, size_t ws_size,
                              hipStream_t stream) {
  const float* x    = (const float*)d_in[0];
  const int*   nbrs = (const int*)d_in[1];
  const float* dist = (const float*)d_in[2];
  const float* W    = (const float*)d_in[3];
  const float* bias = (const float*)d_in[4];
  float* out = (float*)d_out;

  char* ws = (char*)d_ws;
  __bf16* xb2h = (__bf16*)(ws);                          // 2*2000*2048 = 8,192,000 B
  __bf16* Wf2  = (__bf16*)(ws + 8192000);                // 65*8192     =   532,480 B
  __bf16* db   = (__bf16*)(ws + 8192000 + 532480);       // 2000*32*2   =   128,000 B

  kprep<<<NN + 65, 256, 0, stream>>>(x, dist, W, xb2h, db, Wf2);
  kmain<<<(NN / 16) * 2, 512, 0, stream>>>(nbrs, bias, xb2h, Wf2, db, out);
}